// Round 16
// baseline (335.902 us; speedup 1.0000x reference)
//
#include <hip/hip_runtime.h>
#include <stdint.h>

#define NN 8192
#define DD 512
#define SPLIT 4
#define ITERS_PER_SPLIT 16   // 64 total K-iters of 128 / SPLIT

typedef uint16_t u16;
typedef __bf16 bf16x8_t __attribute__((ext_vector_type(8)));
typedef float f32x4_t __attribute__((ext_vector_type(4)));
typedef uint32_t u32x4_t __attribute__((ext_vector_type(4)));

__device__ __forceinline__ u16 f2bf(float x) {
  uint32_t u = __builtin_bit_cast(uint32_t, x);
  u += 0x7FFFu + ((u >> 16) & 1u);   // round-to-nearest-even
  return (u16)(u >> 16);
}
__device__ __forceinline__ float h2f(uint32_t bits) {
  return (float)__builtin_bit_cast(_Float16, (u16)bits);
}

__device__ __forceinline__ unsigned encf(float f) {
  unsigned u = __builtin_bit_cast(unsigned, f);
  return (u & 0x80000000u) ? ~u : (u | 0x80000000u);
}
__device__ __forceinline__ float decf(unsigned e) {
  unsigned u = (e & 0x80000000u) ? (e & 0x7FFFFFFFu) : ~e;
  return __builtin_bit_cast(float, u);
}

// ---------------------------------------------------------------- W[k][n] -> WT[n][k] bf16, init maxenc
__global__ __launch_bounds__(256) void k_convert_W(const float* __restrict__ W,
                                                   u16* __restrict__ WT,
                                                   unsigned* __restrict__ maxenc) {
  int t = blockIdx.x * blockDim.x + threadIdx.x;  // 32768 threads
  if (t == 0) *maxenc = 0u;
  int n = t >> 6;
  int k8 = (t & 63) << 3;
  u16 tmp[8];
#pragma unroll
  for (int j = 0; j < 8; ++j) tmp[j] = f2bf(W[(size_t)(k8 + j) * DD + n]);
  uint32_t w0 = (uint32_t)tmp[0] | ((uint32_t)tmp[1] << 16);
  uint32_t w1 = (uint32_t)tmp[2] | ((uint32_t)tmp[3] << 16);
  uint32_t w2 = (uint32_t)tmp[4] | ((uint32_t)tmp[5] << 16);
  uint32_t w3 = (uint32_t)tmp[6] | ((uint32_t)tmp[7] << 16);
  *(uint4*)&WT[(size_t)n * DD + k8] = make_uint4(w0, w1, w2, w3);
}

// ---------------------------------------------------------------- h = input @ W  (bf16 MFMA)
// 64x128 tiles, 512 threads (8 waves, each 16 rows x 64 cols), grid (128,4).
__global__ __launch_bounds__(512) void k_gemm_h(const float* __restrict__ Af,
                                                const u16* __restrict__ BT,
                                                u16* __restrict__ HT,
                                                const float* __restrict__ a1,
                                                const float* __restrict__ a2,
                                                float* __restrict__ e1part,
                                                float* __restrict__ e2part) {
  __shared__ __align__(16) u16 As[64 * 32];    // 4KB
  __shared__ __align__(16) u16 Bs[128 * 32];   // 8KB
  const int tid = threadIdx.x;
  const int wid = tid >> 6, lane = tid & 63;   // 8 waves
  const int wr = wid >> 1, wc = wid & 1;       // wave: rows wr*16, cols wc*64
  const int lr = lane & 15, kg = lane >> 4;
  const int rowBase = blockIdx.x * 64;
  const int colBase = blockIdx.y * 128;
  const int sr = tid >> 2, sc = tid & 3;       // staging coords
  f32x4_t acc[4] = {};
  for (int kt = 0; kt < 16; ++kt) {
    const int k0 = kt * 32 + sc * 8;
    if (tid < 256) {  // wave-uniform branch (waves 0..3): stage A rows 0..63
      float4 f0 = *(const float4*)&Af[(size_t)(rowBase + sr) * DD + k0];
      float4 f1 = *(const float4*)&Af[(size_t)(rowBase + sr) * DD + k0 + 4];
      *(uint4*)&As[sr * 32 + sc * 8] = make_uint4(
          (uint32_t)f2bf(f0.x) | ((uint32_t)f2bf(f0.y) << 16),
          (uint32_t)f2bf(f0.z) | ((uint32_t)f2bf(f0.w) << 16),
          (uint32_t)f2bf(f1.x) | ((uint32_t)f2bf(f1.y) << 16),
          (uint32_t)f2bf(f1.z) | ((uint32_t)f2bf(f1.w) << 16));
    }
    *(uint4*)&Bs[sr * 32 + sc * 8] = *(const uint4*)&BT[(size_t)(colBase + sr) * DD + k0];
    __syncthreads();
    bf16x8_t af = *(const bf16x8_t*)&As[(wr * 16 + lr) * 32 + kg * 8];
    bf16x8_t bfv[4];
#pragma unroll
    for (int nt = 0; nt < 4; ++nt)
      bfv[nt] = *(const bf16x8_t*)&Bs[(wc * 64 + nt * 16 + lr) * 32 + kg * 8];
#pragma unroll
    for (int nt = 0; nt < 4; ++nt)
      acc[nt] = __builtin_amdgcn_mfma_f32_16x16x32_bf16(af, bfv[nt], acc[nt], 0, 0, 0);
    __syncthreads();
  }
  float a1v[4], a2v[4];
#pragma unroll
  for (int nt = 0; nt < 4; ++nt) {
    const int col = colBase + wc * 64 + nt * 16 + lr;
    a1v[nt] = a1[col];
    a2v[nt] = a2[col];
  }
  const int cg = blockIdx.y * 2 + wc;  // 64-col group 0..7
  const int row0 = rowBase + wr * 16 + kg * 4;
#pragma unroll
  for (int nt = 0; nt < 4; ++nt) {
    const int col = colBase + wc * 64 + nt * 16 + lr;
    uint32_t lo = (uint32_t)f2bf(acc[nt][0]) | ((uint32_t)f2bf(acc[nt][1]) << 16);
    uint32_t hi = (uint32_t)f2bf(acc[nt][2]) | ((uint32_t)f2bf(acc[nt][3]) << 16);
    *(uint2*)&HT[(size_t)col * NN + row0] = make_uint2(lo, hi);
  }
#pragma unroll
  for (int r = 0; r < 4; ++r) {
    float t1 = 0.f, t2 = 0.f;
#pragma unroll
    for (int nt = 0; nt < 4; ++nt) {
      t1 += acc[nt][r] * a1v[nt];
      t2 += acc[nt][r] * a2v[nt];
    }
#pragma unroll
    for (int m = 1; m <= 8; m <<= 1) {
      t1 += __shfl_xor(t1, m);
      t2 += __shfl_xor(t2, m);
    }
    if (lr == 0) {
      e1part[(size_t)cg * NN + row0 + r] = t1;
      e2part[(size_t)cg * NN + row0 + r] = t2;
    }
  }
}

// ---------------------------------------------------------------- reduce e1/e2 slices, maxE2, exp tables
__global__ __launch_bounds__(256) void k_e12small(const float* __restrict__ e1part,
                                                  const float* __restrict__ e2part,
                                                  float* __restrict__ e1, float* __restrict__ e2,
                                                  float* __restrict__ E2t, float* __restrict__ F2t,
                                                  unsigned* __restrict__ maxenc) {
  const int row = blockIdx.x * 256 + threadIdx.x;
  float s1 = 0.f, s2 = 0.f;
#pragma unroll
  for (int cg = 0; cg < 8; ++cg) {
    s1 += e1part[(size_t)cg * NN + row];
    s2 += e2part[(size_t)cg * NN + row];
  }
  e1[row] = s1;
  e2[row] = s2;
  E2t[row] = __expf(s2);
  F2t[row] = __expf(0.2f * s2);
  atomicMax(maxenc, encf(s2));
}

// ---------------------------------------------------------------- fused masked-softmax @ h (split-K partials)
// R16 = R14 geometry + launch_bounds(512, 4) + R15 rank-1 tables.
// R14 failed because bare launch_bounds(512) let the compiler target 8 waves/EU ->
// unified VGPR+AGPR budget 64 -> acc (64 AGPR) spilled (WRITE 62MB). R10's counters
// prove the fix: VGPR_Count=64 with 64 acc/thread and no spill = acc in AGPRs, i.e.
// the kernel really runs at 64 VGPR + 64 AGPR = 128 = the 4-waves/EU budget. Declaring
// (512, 4) grants exactly that budget. Block = 512 thr / 8 waves / 64 rows x 512 cols,
// LDS 60KB -> 2 blocks/CU with INDEPENDENT barriers: block A's adj/VALU producer phase
// overlaps block B's LDS/MFMA consumer phase (m114) — overlap without register coupling.
// P map verbatim (tau0=tid, tau1=tid+512); math identical to R15.
__global__ __launch_bounds__(512, 4) void k_fused(const float* __restrict__ adj,
                                                  const u16* __restrict__ HT,
                                                  const float* __restrict__ e1,
                                                  const float* __restrict__ E2t,
                                                  const float* __restrict__ F2t,
                                                  const unsigned* __restrict__ maxenc,
                                                  u16* __restrict__ numpart,
                                                  float* __restrict__ denpart) {
  __shared__ __align__(16) u16 P[2][64 * 128];        // 32KB double-buffered
  __shared__ __align__(16) float E2s[256 * 12];       // 12KB, stride-12 conflict-free
  __shared__ __align__(16) float F2s[256 * 12];       // 12KB
  __shared__ float partsum[1024];                     // 4KB   (total 60KB)
  const int tid = threadIdx.x;
  const int wid = tid >> 6;        // 0..7
  const int lane = tid & 63;
  const int lr = lane & 15;
  const int kg = lane >> 4;
  const int b = blockIdx.x;
  const int xcd = b & 7;
  const int bz = xcd >> 1;                           // 0..3, fixed per XCD pair
  const int rowBlock = (b >> 3) + ((xcd & 1) << 6);  // 0..127, bijective
  const int rowBase = rowBlock * 64;
  const int kk0 = bz * ITERS_PER_SPLIT;
  // producer coords: thread owns rows r0l and r0l+32, k-chunk c (8 cols)
  const int c = (tid >> 4) & 15;
  const int m = tid & 15;
  const int mt0 = tid >> 8;        // 0..1
  const int r0l = mt0 * 16 + m;    // 0..31
  const float e1r0 = e1[rowBase + r0l];
  const float e1r1 = e1[rowBase + r0l + 32];
  const float mE2 = decf(*maxenc);
  const float xb0 = e1r0 + mE2, xb1 = e1r1 + mE2;
  const float bnd0 = fmaxf(xb0, 0.2f * xb0);  // leakyrelu(e1+maxE2) >= all row scores
  const float bnd1 = fmaxf(xb1, 0.2f * xb1);
  const float sr0 = __expf(e1r0 - bnd0), tr0 = __expf(0.2f * e1r0 - bnd0);
  const float sr1 = __expf(e1r1 - bnd1), tr1 = __expf(0.2f * e1r1 - bnd1);
  {
    const float* Eg = E2t + kk0 * 128;
    const float* Fg = F2t + kk0 * 128;
    if (tid < 256) {
      float4 u0 = *(const float4*)(Eg + tid * 8);
      float4 u1 = *(const float4*)(Eg + tid * 8 + 4);
      *(float4*)&E2s[tid * 12] = u0;
      *(float4*)&E2s[tid * 12 + 4] = u1;
      float4 v0 = *(const float4*)(Fg + tid * 8);
      float4 v1 = *(const float4*)(Fg + tid * 8 + 4);
      *(float4*)&F2s[tid * 12] = v0;
      *(float4*)&F2s[tid * 12 + 4] = v1;
    }
  }
  const float* adjp0 = adj + (size_t)(rowBase + r0l) * NN + c * 8;
  const float* adjp1 = adjp0 + (size_t)32 * NN;
  const int n0 = wid * 64;         // wave owns 64 cols
  const u16* btp0 = HT + (size_t)(n0 + 0 + lr) * NN + kg * 8;
  const u16* btp1 = HT + (size_t)(n0 + 16 + lr) * NN + kg * 8;
  const u16* btp2 = HT + (size_t)(n0 + 32 + lr) * NN + kg * 8;
  const u16* btp3 = HT + (size_t)(n0 + 48 + lr) * NN + kg * 8;
  float dsum0 = 0.f, dsum1 = 0.f;
  f32x4_t acc[4][4] = {};
  // adj distance-1 reg prefetch
  f32x4_t a00 = __builtin_nontemporal_load((const f32x4_t*)(adjp0 + kk0 * 128));
  f32x4_t a01 = __builtin_nontemporal_load((const f32x4_t*)(adjp0 + kk0 * 128 + 4));
  f32x4_t a10 = __builtin_nontemporal_load((const f32x4_t*)(adjp1 + kk0 * 128));
  f32x4_t a11 = __builtin_nontemporal_load((const f32x4_t*)(adjp1 + kk0 * 128 + 4));
  __syncthreads();  // E2s/F2s ready
#pragma unroll 1
  for (int t = 0; t < ITERS_PER_SPLIT; ++t) {
    const int colBase = (kk0 + t) * 128;
    const float* Ee = &E2s[(t * 16 + c) * 12];
    const float* Fe = &F2s[(t * 16 + c) * 12];
    f32x4_t E0 = *(const f32x4_t*)Ee;
    f32x4_t E1 = *(const f32x4_t*)(Ee + 4);
    f32x4_t F0 = *(const f32x4_t*)Fe;
    f32x4_t F1 = *(const f32x4_t*)(Fe + 4);
    float EE[8] = {E0[0], E0[1], E0[2], E0[3], E1[0], E1[1], E1[2], E1[3]};
    float FF[8] = {F0[0], F0[1], F0[2], F0[3], F1[0], F1[1], F1[2], F1[3]};
    float aa0[8] = {a00[0], a00[1], a00[2], a00[3], a01[0], a01[1], a01[2], a01[3]};
    float aa1[8] = {a10[0], a10[1], a10[2], a10[3], a11[0], a11[1], a11[2], a11[3]};
    float pv0[8], pv1[8];
#pragma unroll
    for (int j = 0; j < 8; ++j) {
      float p0 = fmaxf(sr0 * EE[j], tr0 * FF[j]);   // = exp(lrelu(e1r0+e2k)-bnd0)
      p0 = (aa0[j] > -1e19f) ? p0 : 0.f;
      pv0[j] = p0;
      dsum0 += p0;
      float p1 = fmaxf(sr1 * EE[j], tr1 * FF[j]);
      p1 = (aa1[j] > -1e19f) ? p1 : 0.f;
      pv1[j] = p1;
      dsum1 += p1;
    }
    {
      uint32_t w0 = (uint32_t)f2bf(pv0[0]) | ((uint32_t)f2bf(pv0[1]) << 16);
      uint32_t w1 = (uint32_t)f2bf(pv0[2]) | ((uint32_t)f2bf(pv0[3]) << 16);
      uint32_t w2 = (uint32_t)f2bf(pv0[4]) | ((uint32_t)f2bf(pv0[5]) << 16);
      uint32_t w3 = (uint32_t)f2bf(pv0[6]) | ((uint32_t)f2bf(pv0[7]) << 16);
      *(uint4*)&P[t & 1][tid * 8] = make_uint4(w0, w1, w2, w3);
      uint32_t v0 = (uint32_t)f2bf(pv1[0]) | ((uint32_t)f2bf(pv1[1]) << 16);
      uint32_t v1 = (uint32_t)f2bf(pv1[2]) | ((uint32_t)f2bf(pv1[3]) << 16);
      uint32_t v2 = (uint32_t)f2bf(pv1[4]) | ((uint32_t)f2bf(pv1[5]) << 16);
      uint32_t v3 = (uint32_t)f2bf(pv1[6]) | ((uint32_t)f2bf(pv1[7]) << 16);
      *(uint4*)&P[t & 1][(tid + 512) * 8] = make_uint4(v0, v1, v2, v3);
    }
    if (t + 1 < ITERS_PER_SPLIT) {  // prefetch next iter adj; stays in flight across barrier
      const float* q0 = adjp0 + colBase + 128;
      const float* q1 = adjp1 + colBase + 128;
      a00 = __builtin_nontemporal_load((const f32x4_t*)q0);
      a01 = __builtin_nontemporal_load((const f32x4_t*)(q0 + 4));
      a10 = __builtin_nontemporal_load((const f32x4_t*)q1);
      a11 = __builtin_nontemporal_load((const f32x4_t*)(q1 + 4));
    }
    // preload ks=0 B-fragments (independent of P; in flight across barrier)
    bf16x8_t bc0 = *(const bf16x8_t*)(btp0 + colBase);
    bf16x8_t bc1 = *(const bf16x8_t*)(btp1 + colBase);
    bf16x8_t bc2 = *(const bf16x8_t*)(btp2 + colBase);
    bf16x8_t bc3 = *(const bf16x8_t*)(btp3 + colBase);
    asm volatile("s_waitcnt lgkmcnt(0)" ::: "memory");  // P writes visible; vmcnt NOT drained
    __builtin_amdgcn_s_barrier();
    const u16* pb = &P[t & 1][0];
#pragma unroll
    for (int ks = 0; ks < 4; ++ks) {
      if (ks > 0) {  // no dbuf: cross-block overlap hides the L2 latency
        const int co = colBase + ks * 32;
        bc0 = *(const bf16x8_t*)(btp0 + co);
        bc1 = *(const bf16x8_t*)(btp1 + co);
        bc2 = *(const bf16x8_t*)(btp2 + co);
        bc3 = *(const bf16x8_t*)(btp3 + co);
      }
#pragma unroll
      for (int mt = 0; mt < 4; ++mt) {
        bf16x8_t af = *(const bf16x8_t*)(pb + mt * 2048 + ks * 512 + lane * 8);
        acc[mt][0] = __builtin_amdgcn_mfma_f32_16x16x32_bf16(af, bc0, acc[mt][0], 0, 0, 0);
        acc[mt][1] = __builtin_amdgcn_mfma_f32_16x16x32_bf16(af, bc1, acc[mt][1], 0, 0, 0);
        acc[mt][2] = __builtin_amdgcn_mfma_f32_16x16x32_bf16(af, bc2, acc[mt][2], 0, 0, 0);
        acc[mt][3] = __builtin_amdgcn_mfma_f32_16x16x32_bf16(af, bc3, acc[mt][3], 0, 0, 0);
      }
    }
  }
  // deterministic per-row denominator reduction (16 partials per row, fixed order)
  partsum[tid] = dsum0;
  partsum[tid + 512] = dsum1;
  __syncthreads();
  if (tid < 64) {
    const int rr = tid;
    const int rlo = rr & 31;
    const int off = (rr >> 5) << 9;  // +512 for rows 32..63
    float s = 0.f;
#pragma unroll
    for (int cc = 0; cc < 16; ++cc)
      s += partsum[off + (rlo >> 4) * 256 + cc * 16 + (rlo & 15)];
    denpart[(size_t)bz * NN + rowBase + rr] = s;
  }
  u16* np = numpart + (size_t)bz * NN * DD;
#pragma unroll
  for (int mt = 0; mt < 4; ++mt)
#pragma unroll
    for (int nt = 0; nt < 4; ++nt)
#pragma unroll
      for (int r = 0; r < 4; ++r) {
        const int rowL = mt * 16 + kg * 4 + r;
        _Float16 hv = (_Float16)acc[mt][nt][r];
        __builtin_nontemporal_store(__builtin_bit_cast(u16, hv),
                                    &np[(size_t)(rowBase + rowL) * DD + n0 + nt * 16 + lr]);
      }
}

// ---------------------------------------------------------------- combine f16 partials: out = tanh(num/den)
__global__ __launch_bounds__(256) void k_combine(const u16* __restrict__ num,
                                                 const float* __restrict__ den,
                                                 float* __restrict__ out) {
  const size_t idx = (size_t)blockIdx.x * 256 + threadIdx.x;  // 8-half units
  const int row = (int)(idx >> 6);                            // 64 chunks of 8 per row
  float d = den[row] + den[NN + row] + den[2 * NN + row] + den[3 * NN + row];
  const u32x4_t* nv = (const u32x4_t*)num;
  const size_t stride = (size_t)NN * DD / 8;
  float s[8] = {};
#pragma unroll
  for (int sl = 0; sl < 4; ++sl) {
    u32x4_t q = __builtin_nontemporal_load(nv + sl * stride + idx);
    s[0] += h2f(q[0] & 0xffff); s[1] += h2f(q[0] >> 16);
    s[2] += h2f(q[1] & 0xffff); s[3] += h2f(q[1] >> 16);
    s[4] += h2f(q[2] & 0xffff); s[5] += h2f(q[2] >> 16);
    s[6] += h2f(q[3] & 0xffff); s[7] += h2f(q[3] >> 16);
  }
  const float inv = (d > 0.f) ? 1.f / d : 0.f;
  f32x4_t o0, o1;
#pragma unroll
  for (int j = 0; j < 4; ++j) o0[j] = 1.f - 2.f / (__expf(2.f * (s[j] * inv)) + 1.f);
#pragma unroll
  for (int j = 0; j < 4; ++j) o1[j] = 1.f - 2.f / (__expf(2.f * (s[4 + j] * inv)) + 1.f);
  __builtin_nontemporal_store(o0, ((f32x4_t*)out) + idx * 2);
  __builtin_nontemporal_store(o1, ((f32x4_t*)out) + idx * 2 + 1);
}

// ----------------------------------------------------------------
extern "C" void kernel_launch(void* const* d_in, const int* in_sizes, int n_in,
                              void* d_out, int out_size, void* d_ws, size_t ws_size,
                              hipStream_t stream) {
  const float* input = (const float*)d_in[0];
  const float* adj   = (const float*)d_in[1];
  const float* W     = (const float*)d_in[2];
  const float* a1    = (const float*)d_in[3];
  const float* a2    = (const float*)d_in[4];
  float* out = (float*)d_out;
  char* ws = (char*)d_ws;

  u16* hT        = (u16*)ws;                      // 8192*512*2  = 8,388,608
  float* e1      = (float*)(ws + 8388608);        // 32,768
  float* e2      = (float*)(ws + 8421376);        // 32,768
  float* E2t     = (float*)(ws + 8454144);        // 32,768
  float* F2t     = (float*)(ws + 8486912);        // 32,768
  unsigned* mx   = (unsigned*)(ws + 8519680);     // 4 (pad to 256)
  float* denp    = (float*)(ws + 8519936);        // SPLIT*8192*4 = 131,072
  float* e1p     = (float*)(ws + 8651008);        // 8*8192*4 = 262,144
  float* e2p     = (float*)(ws + 8913152);        // 262,144
  u16* nump      = (u16*)(ws + 9175296);          // SPLIT*8192*512*2 = 33,554,432 -> end 42,729,728
  // WT is dead before k_fused writes nump -> overlay:
  u16* WT        = (u16*)(ws + 9175296);          // 524,288

  hipLaunchKernelGGL(k_convert_W, dim3(128), dim3(256), 0, stream, W, WT, mx);
  hipLaunchKernelGGL(k_gemm_h, dim3(128, 4), dim3(512), 0, stream, input, WT, hT, a1, a2, e1p, e2p);
  hipLaunchKernelGGL(k_e12small, dim3(32), dim3(256), 0, stream, e1p, e2p, e1, e2, E2t, F2t, mx);
  hipLaunchKernelGGL(k_fused, dim3(128 * SPLIT), dim3(512), 0, stream, adj, hT, e1, E2t, F2t, mx, nump, denp);
  hipLaunchKernelGGL(k_combine, dim3(2048), dim3(256), 0, stream, nump, denp, out);
}

// Round 17
// 175.829 us; speedup vs baseline: 1.9104x; 1.9104x over previous
//
#include <hip/hip_runtime.h>
#include <stdint.h>

#define NN 8192
#define DD 512
#define SPLIT 4
#define ITERS_PER_SPLIT 16   // 64 total K-iters of 128 / SPLIT

typedef uint16_t u16;
typedef __bf16 bf16x8_t __attribute__((ext_vector_type(8)));
typedef float f32x4_t __attribute__((ext_vector_type(4)));
typedef uint32_t u32x4_t __attribute__((ext_vector_type(4)));

__device__ __forceinline__ u16 f2bf(float x) {
  uint32_t u = __builtin_bit_cast(uint32_t, x);
  u += 0x7FFFu + ((u >> 16) & 1u);   // round-to-nearest-even
  return (u16)(u >> 16);
}
__device__ __forceinline__ float h2f(uint32_t bits) {
  return (float)__builtin_bit_cast(_Float16, (u16)bits);
}

__device__ __forceinline__ unsigned encf(float f) {
  unsigned u = __builtin_bit_cast(unsigned, f);
  return (u & 0x80000000u) ? ~u : (u | 0x80000000u);
}
__device__ __forceinline__ float decf(unsigned e) {
  unsigned u = (e & 0x80000000u) ? (e & 0x7FFFFFFFu) : ~e;
  return __builtin_bit_cast(float, u);
}

// ---------------------------------------------------------------- W[k][n] -> WT[n][k] bf16, init maxenc
__global__ __launch_bounds__(256) void k_convert_W(const float* __restrict__ W,
                                                   u16* __restrict__ WT,
                                                   unsigned* __restrict__ maxenc) {
  int t = blockIdx.x * blockDim.x + threadIdx.x;  // 32768 threads
  if (t == 0) *maxenc = 0u;
  int n = t >> 6;
  int k8 = (t & 63) << 3;
  u16 tmp[8];
#pragma unroll
  for (int j = 0; j < 8; ++j) tmp[j] = f2bf(W[(size_t)(k8 + j) * DD + n]);
  uint32_t w0 = (uint32_t)tmp[0] | ((uint32_t)tmp[1] << 16);
  uint32_t w1 = (uint32_t)tmp[2] | ((uint32_t)tmp[3] << 16);
  uint32_t w2 = (uint32_t)tmp[4] | ((uint32_t)tmp[5] << 16);
  uint32_t w3 = (uint32_t)tmp[6] | ((uint32_t)tmp[7] << 16);
  *(uint4*)&WT[(size_t)n * DD + k8] = make_uint4(w0, w1, w2, w3);
}

// ---------------------------------------------------------------- h = input @ W  (bf16 MFMA)
// 64x128 tiles, 512 threads (8 waves, each 16 rows x 64 cols), grid (128,4).
__global__ __launch_bounds__(512) void k_gemm_h(const float* __restrict__ Af,
                                                const u16* __restrict__ BT,
                                                u16* __restrict__ HT,
                                                const float* __restrict__ a1,
                                                const float* __restrict__ a2,
                                                float* __restrict__ e1part,
                                                float* __restrict__ e2part) {
  __shared__ __align__(16) u16 As[64 * 32];    // 4KB
  __shared__ __align__(16) u16 Bs[128 * 32];   // 8KB
  const int tid = threadIdx.x;
  const int wid = tid >> 6, lane = tid & 63;   // 8 waves
  const int wr = wid >> 1, wc = wid & 1;       // wave: rows wr*16, cols wc*64
  const int lr = lane & 15, kg = lane >> 4;
  const int rowBase = blockIdx.x * 64;
  const int colBase = blockIdx.y * 128;
  const int sr = tid >> 2, sc = tid & 3;       // staging coords
  f32x4_t acc[4] = {};
  for (int kt = 0; kt < 16; ++kt) {
    const int k0 = kt * 32 + sc * 8;
    if (tid < 256) {  // wave-uniform branch (waves 0..3): stage A rows 0..63
      float4 f0 = *(const float4*)&Af[(size_t)(rowBase + sr) * DD + k0];
      float4 f1 = *(const float4*)&Af[(size_t)(rowBase + sr) * DD + k0 + 4];
      *(uint4*)&As[sr * 32 + sc * 8] = make_uint4(
          (uint32_t)f2bf(f0.x) | ((uint32_t)f2bf(f0.y) << 16),
          (uint32_t)f2bf(f0.z) | ((uint32_t)f2bf(f0.w) << 16),
          (uint32_t)f2bf(f1.x) | ((uint32_t)f2bf(f1.y) << 16),
          (uint32_t)f2bf(f1.z) | ((uint32_t)f2bf(f1.w) << 16));
    }
    *(uint4*)&Bs[sr * 32 + sc * 8] = *(const uint4*)&BT[(size_t)(colBase + sr) * DD + k0];
    __syncthreads();
    bf16x8_t af = *(const bf16x8_t*)&As[(wr * 16 + lr) * 32 + kg * 8];
    bf16x8_t bfv[4];
#pragma unroll
    for (int nt = 0; nt < 4; ++nt)
      bfv[nt] = *(const bf16x8_t*)&Bs[(wc * 64 + nt * 16 + lr) * 32 + kg * 8];
#pragma unroll
    for (int nt = 0; nt < 4; ++nt)
      acc[nt] = __builtin_amdgcn_mfma_f32_16x16x32_bf16(af, bfv[nt], acc[nt], 0, 0, 0);
    __syncthreads();
  }
  float a1v[4], a2v[4];
#pragma unroll
  for (int nt = 0; nt < 4; ++nt) {
    const int col = colBase + wc * 64 + nt * 16 + lr;
    a1v[nt] = a1[col];
    a2v[nt] = a2[col];
  }
  const int cg = blockIdx.y * 2 + wc;  // 64-col group 0..7
  const int row0 = rowBase + wr * 16 + kg * 4;
#pragma unroll
  for (int nt = 0; nt < 4; ++nt) {
    const int col = colBase + wc * 64 + nt * 16 + lr;
    uint32_t lo = (uint32_t)f2bf(acc[nt][0]) | ((uint32_t)f2bf(acc[nt][1]) << 16);
    uint32_t hi = (uint32_t)f2bf(acc[nt][2]) | ((uint32_t)f2bf(acc[nt][3]) << 16);
    *(uint2*)&HT[(size_t)col * NN + row0] = make_uint2(lo, hi);
  }
#pragma unroll
  for (int r = 0; r < 4; ++r) {
    float t1 = 0.f, t2 = 0.f;
#pragma unroll
    for (int nt = 0; nt < 4; ++nt) {
      t1 += acc[nt][r] * a1v[nt];
      t2 += acc[nt][r] * a2v[nt];
    }
#pragma unroll
    for (int m = 1; m <= 8; m <<= 1) {
      t1 += __shfl_xor(t1, m);
      t2 += __shfl_xor(t2, m);
    }
    if (lr == 0) {
      e1part[(size_t)cg * NN + row0 + r] = t1;
      e2part[(size_t)cg * NN + row0 + r] = t2;
    }
  }
}

// ---------------------------------------------------------------- reduce e1/e2 slices, maxE2, exp tables
// E2t[k]=exp(e2[k]), F2t[k]=exp(0.2*e2[k]): rank-1 factor tables for the fused build
// (exp(lrelu(x)-bnd) = max(s_r*E2[k], t_r*F2[k]) by monotonicity of exp).
__global__ __launch_bounds__(256) void k_e12small(const float* __restrict__ e1part,
                                                  const float* __restrict__ e2part,
                                                  float* __restrict__ e1, float* __restrict__ e2,
                                                  float* __restrict__ E2t, float* __restrict__ F2t,
                                                  unsigned* __restrict__ maxenc) {
  const int row = blockIdx.x * 256 + threadIdx.x;
  float s1 = 0.f, s2 = 0.f;
#pragma unroll
  for (int cg = 0; cg < 8; ++cg) {
    s1 += e1part[(size_t)cg * NN + row];
    s2 += e2part[(size_t)cg * NN + row];
  }
  e1[row] = s1;
  e2[row] = s2;
  E2t[row] = __expf(s2);
  F2t[row] = __expf(0.2f * s2);
  atomicMax(maxenc, encf(s2));
}

// ---------------------------------------------------------------- fused masked-softmax @ h (split-K partials)
// R15 structure — the register-constrained optimum of this decomposition. Invariant:
// 128-row x 512-col output slice per CU = 64K accumulators; only 16 waves/CU x 128-reg
// budget (64 VGPR + 64 AGPR acc) fits. All finer-grained overlap schedules (R9, R11-R14,
// R16) exceeded the ~zero VGPR slack and spilled (WRITE_SIZE-verified) or doubled
// HT/adj traffic. Rank-1 P build: p = edge ? max(s_r*E2[k], t_r*F2[k]) : 0 (no exp).
__global__ __launch_bounds__(1024) void k_fused(const float* __restrict__ adj,
                                                const u16* __restrict__ HT,
                                                const float* __restrict__ e1,
                                                const float* __restrict__ E2t,
                                                const float* __restrict__ F2t,
                                                const unsigned* __restrict__ maxenc,
                                                u16* __restrict__ numpart,
                                                float* __restrict__ denpart) {
  __shared__ __align__(16) u16 P[2][128 * 128];       // 64KB double-buffered
  __shared__ __align__(16) float E2s[256 * 12];       // 12KB, stride-12 conflict-free
  __shared__ __align__(16) float F2s[256 * 12];       // 12KB
  __shared__ float partsum[2048];                     // 8KB   (total 96KB)
  const int tid = threadIdx.x;
  const int wid = tid >> 6;        // 0..15
  const int lane = tid & 63;
  const int lr = lane & 15;
  const int kg = lane >> 4;
  const int b = blockIdx.x;
  const int xcd = b & 7;
  const int bz = xcd >> 1;                           // 0..3, fixed per XCD
  const int rowBlock = (b >> 3) + ((xcd & 1) << 5);  // 0..63, bijective
  const int rowBase = rowBlock * 128;
  const int kk0 = bz * ITERS_PER_SPLIT;
  const int c = (tid >> 4) & 15;   // 8-col k-chunk within 128-tile
  const int m = tid & 15;
  const int mt0 = tid >> 8;        // 0..3
  const int r0l = mt0 * 16 + m;    // local rows r0l (0..63) and r0l+64
  const float e1r0 = e1[rowBase + r0l];
  const float e1r1 = e1[rowBase + r0l + 64];
  const float mE2 = decf(*maxenc);
  const float xb0 = e1r0 + mE2, xb1 = e1r1 + mE2;
  const float bnd0 = fmaxf(xb0, 0.2f * xb0);  // leakyrelu(e1+maxE2) >= all row scores
  const float bnd1 = fmaxf(xb1, 0.2f * xb1);
  // rank-1 per-row factors
  const float sr0 = __expf(e1r0 - bnd0), tr0 = __expf(0.2f * e1r0 - bnd0);
  const float sr1 = __expf(e1r1 - bnd1), tr1 = __expf(0.2f * e1r1 - bnd1);
  {
    const float* Eg = E2t + kk0 * 128;
    const float* Fg = F2t + kk0 * 128;
    if (tid < 256) {
      float4 u0 = *(const float4*)(Eg + tid * 8);
      float4 u1 = *(const float4*)(Eg + tid * 8 + 4);
      *(float4*)&E2s[tid * 12] = u0;
      *(float4*)&E2s[tid * 12 + 4] = u1;
      float4 v0 = *(const float4*)(Fg + tid * 8);
      float4 v1 = *(const float4*)(Fg + tid * 8 + 4);
      *(float4*)&F2s[tid * 12] = v0;
      *(float4*)&F2s[tid * 12 + 4] = v1;
    }
  }
  const float* adjp0 = adj + (size_t)(rowBase + r0l) * NN + c * 8;
  const float* adjp1 = adjp0 + (size_t)64 * NN;
  const int n0 = wid * 32;
  const u16* btp0 = HT + (size_t)(n0 + 0 + lr) * NN + kg * 8;
  const u16* btp1 = HT + (size_t)(n0 + 16 + lr) * NN + kg * 8;
  float dsum0 = 0.f, dsum1 = 0.f;
  f32x4_t acc[8][2] = {};
  f32x4_t a00 = __builtin_nontemporal_load((const f32x4_t*)(adjp0 + kk0 * 128));
  f32x4_t a01 = __builtin_nontemporal_load((const f32x4_t*)(adjp0 + kk0 * 128 + 4));
  f32x4_t a10 = __builtin_nontemporal_load((const f32x4_t*)(adjp1 + kk0 * 128));
  f32x4_t a11 = __builtin_nontemporal_load((const f32x4_t*)(adjp1 + kk0 * 128 + 4));
  __syncthreads();  // E2s/F2s ready
  for (int t = 0; t < ITERS_PER_SPLIT; ++t) {
    const int colBase = (kk0 + t) * 128;
    const float* Ee = &E2s[(t * 16 + c) * 12];
    const float* Fe = &F2s[(t * 16 + c) * 12];
    f32x4_t E0 = *(const f32x4_t*)Ee;
    f32x4_t E1 = *(const f32x4_t*)(Ee + 4);
    f32x4_t F0 = *(const f32x4_t*)Fe;
    f32x4_t F1 = *(const f32x4_t*)(Fe + 4);
    float EE[8] = {E0[0], E0[1], E0[2], E0[3], E1[0], E1[1], E1[2], E1[3]};
    float FF[8] = {F0[0], F0[1], F0[2], F0[3], F1[0], F1[1], F1[2], F1[3]};
    float aa0[8] = {a00[0], a00[1], a00[2], a00[3], a01[0], a01[1], a01[2], a01[3]};
    float aa1[8] = {a10[0], a10[1], a10[2], a10[3], a11[0], a11[1], a11[2], a11[3]};
    float pv0[8], pv1[8];
#pragma unroll
    for (int j = 0; j < 8; ++j) {
      float p0 = fmaxf(sr0 * EE[j], tr0 * FF[j]);   // = exp(lrelu(e1r0+e2k)-bnd0)
      p0 = (aa0[j] > -1e19f) ? p0 : 0.f;
      pv0[j] = p0;
      dsum0 += p0;
      float p1 = fmaxf(sr1 * EE[j], tr1 * FF[j]);
      p1 = (aa1[j] > -1e19f) ? p1 : 0.f;
      pv1[j] = p1;
      dsum1 += p1;
    }
    {
      uint32_t w0 = (uint32_t)f2bf(pv0[0]) | ((uint32_t)f2bf(pv0[1]) << 16);
      uint32_t w1 = (uint32_t)f2bf(pv0[2]) | ((uint32_t)f2bf(pv0[3]) << 16);
      uint32_t w2 = (uint32_t)f2bf(pv0[4]) | ((uint32_t)f2bf(pv0[5]) << 16);
      uint32_t w3 = (uint32_t)f2bf(pv0[6]) | ((uint32_t)f2bf(pv0[7]) << 16);
      *(uint4*)&P[t & 1][tid * 8] = make_uint4(w0, w1, w2, w3);
      uint32_t v0 = (uint32_t)f2bf(pv1[0]) | ((uint32_t)f2bf(pv1[1]) << 16);
      uint32_t v1 = (uint32_t)f2bf(pv1[2]) | ((uint32_t)f2bf(pv1[3]) << 16);
      uint32_t v2 = (uint32_t)f2bf(pv1[4]) | ((uint32_t)f2bf(pv1[5]) << 16);
      uint32_t v3 = (uint32_t)f2bf(pv1[6]) | ((uint32_t)f2bf(pv1[7]) << 16);
      *(uint4*)&P[t & 1][(tid + 1024) * 8] = make_uint4(v0, v1, v2, v3);
    }
    if (t + 1 < ITERS_PER_SPLIT) {  // prefetch next iter adj; stays in flight across barrier
      const float* q0 = adjp0 + colBase + 128;
      const float* q1 = adjp1 + colBase + 128;
      a00 = __builtin_nontemporal_load((const f32x4_t*)q0);
      a01 = __builtin_nontemporal_load((const f32x4_t*)(q0 + 4));
      a10 = __builtin_nontemporal_load((const f32x4_t*)q1);
      a11 = __builtin_nontemporal_load((const f32x4_t*)(q1 + 4));
    }
    // preload ks=0 B-fragments (independent of P; in flight across barrier)
    bf16x8_t bc0 = *(const bf16x8_t*)(btp0 + colBase);
    bf16x8_t bc1 = *(const bf16x8_t*)(btp1 + colBase);
    asm volatile("s_waitcnt lgkmcnt(0)" ::: "memory");  // P writes visible; vmcnt NOT drained
    __builtin_amdgcn_s_barrier();
    const u16* pb = &P[t & 1][0];
#pragma unroll
    for (int ks = 0; ks < 4; ++ks) {
      bf16x8_t bn0, bn1;
      if (ks < 3) {  // double-buffer: issue next ks's B-loads before this ks's MFMAs
        const int co = colBase + (ks + 1) * 32;
        bn0 = *(const bf16x8_t*)(btp0 + co);
        bn1 = *(const bf16x8_t*)(btp1 + co);
      }
#pragma unroll
      for (int mt = 0; mt < 8; ++mt) {
        bf16x8_t af = *(const bf16x8_t*)(pb + mt * 2048 + ks * 512 + lane * 8);
        acc[mt][0] = __builtin_amdgcn_mfma_f32_16x16x32_bf16(af, bc0, acc[mt][0], 0, 0, 0);
        acc[mt][1] = __builtin_amdgcn_mfma_f32_16x16x32_bf16(af, bc1, acc[mt][1], 0, 0, 0);
      }
      if (ks < 3) { bc0 = bn0; bc1 = bn1; }
    }
  }
  // deterministic per-row denominator reduction (16 partials per row, fixed order)
  partsum[tid] = dsum0;
  partsum[tid + 1024] = dsum1;
  __syncthreads();
  if (tid < 128) {
    const int rr = tid;
    const int rlo = rr & 63;
    const int off = (rr >> 6) << 10;  // +1024 for rows 64..127
    float s = 0.f;
#pragma unroll
    for (int cc = 0; cc < 16; ++cc)
      s += partsum[off + (rlo >> 4) * 256 + cc * 16 + (rlo & 15)];
    denpart[(size_t)bz * NN + rowBase + rr] = s;
  }
  u16* np = numpart + (size_t)bz * NN * DD;
#pragma unroll
  for (int mt = 0; mt < 8; ++mt)
#pragma unroll
    for (int nt = 0; nt < 2; ++nt)
#pragma unroll
      for (int r = 0; r < 4; ++r) {
        const int rowL = mt * 16 + kg * 4 + r;
        _Float16 hv = (_Float16)acc[mt][nt][r];
        __builtin_nontemporal_store(__builtin_bit_cast(u16, hv),
                                    &np[(size_t)(rowBase + rowL) * DD + n0 + nt * 16 + lr]);
      }
}

// ---------------------------------------------------------------- combine f16 partials: out = tanh(num/den)
__global__ __launch_bounds__(256) void k_combine(const u16* __restrict__ num,
                                                 const float* __restrict__ den,
                                                 float* __restrict__ out) {
  const size_t idx = (size_t)blockIdx.x * 256 + threadIdx.x;  // 8-half units
  const int row = (int)(idx >> 6);                            // 64 chunks of 8 per row
  float d = den[row] + den[NN + row] + den[2 * NN + row] + den[3 * NN + row];
  const u32x4_t* nv = (const u32x4_t*)num;
  const size_t stride = (size_t)NN * DD / 8;
  float s[8] = {};
#pragma unroll
  for (int sl = 0; sl < 4; ++sl) {
    u32x4_t q = __builtin_nontemporal_load(nv + sl * stride + idx);
    s[0] += h2f(q[0] & 0xffff); s[1] += h2f(q[0] >> 16);
    s[2] += h2f(q[1] & 0xffff); s[3] += h2f(q[1] >> 16);
    s[4] += h2f(q[2] & 0xffff); s[5] += h2f(q[2] >> 16);
    s[6] += h2f(q[3] & 0xffff); s[7] += h2f(q[3] >> 16);
  }
  const float inv = (d > 0.f) ? 1.f / d : 0.f;
  f32x4_t o0, o1;
#pragma unroll
  for (int j = 0; j < 4; ++j) o0[j] = 1.f - 2.f / (__expf(2.f * (s[j] * inv)) + 1.f);
#pragma unroll
  for (int j = 0; j < 4; ++j) o1[j] = 1.f - 2.f / (__expf(2.f * (s[4 + j] * inv)) + 1.f);
  __builtin_nontemporal_store(o0, ((f32x4_t*)out) + idx * 2);
  __builtin_nontemporal_store(o1, ((f32x4_t*)out) + idx * 2 + 1);
}

// ----------------------------------------------------------------
extern "C" void kernel_launch(void* const* d_in, const int* in_sizes, int n_in,
                              void* d_out, int out_size, void* d_ws, size_t ws_size,
                              hipStream_t stream) {
  const float* input = (const float*)d_in[0];
  const float* adj   = (const float*)d_in[1];
  const float* W     = (const float*)d_in[2];
  const float* a1    = (const float*)d_in[3];
  const float* a2    = (const float*)d_in[4];
  float* out = (float*)d_out;
  char* ws = (char*)d_ws;

  u16* hT        = (u16*)ws;                      // 8192*512*2  = 8,388,608
  float* e1      = (float*)(ws + 8388608);        // 32,768
  float* e2      = (float*)(ws + 8421376);        // 32,768
  float* E2t     = (float*)(ws + 8454144);        // 32,768
  float* F2t     = (float*)(ws + 8486912);        // 32,768
  unsigned* mx   = (unsigned*)(ws + 8519680);     // 4 (pad to 256)
  float* denp    = (float*)(ws + 8519936);        // SPLIT*8192*4 = 131,072
  float* e1p     = (float*)(ws + 8651008);        // 8*8192*4 = 262,144
  float* e2p     = (float*)(ws + 8913152);        // 262,144
  u16* nump      = (u16*)(ws + 9175296);          // SPLIT*8192*512*2 = 33,554,432 -> end 42,729,728
  // WT is dead before k_fused writes nump -> overlay:
  u16* WT        = (u16*)(ws + 9175296);          // 524,288

  hipLaunchKernelGGL(k_convert_W, dim3(128), dim3(256), 0, stream, W, WT, mx);
  hipLaunchKernelGGL(k_gemm_h, dim3(128, 4), dim3(512), 0, stream, input, WT, hT, a1, a2, e1p, e2p);
  hipLaunchKernelGGL(k_e12small, dim3(32), dim3(256), 0, stream, e1p, e2p, e1, e2, E2t, F2t, mx);
  hipLaunchKernelGGL(k_fused, dim3(64 * SPLIT), dim3(1024), 0, stream, adj, hT, e1, E2t, F2t, mx, nump, denp);
  hipLaunchKernelGGL(k_combine, dim3(2048), dim3(256), 0, stream, nump, denp, out);
}